// Round 3
// baseline (1115.836 us; speedup 1.0000x reference)
//
#include <hip/hip_runtime.h>
#include <math.h>

// ---------------------------------------------------------------------------
// ForgettingAttentionLayer, MI355X bf16-MFMA pipeline.
// B=2 T=2048 C=2048 H=16 D=128.  All big matmuls: mfma_f32_16x16x32_bf16.
// Gates / log-sigmoid / cumsum / softmax bookkeeping: fp32.
// Pipeline: cvt(x) -> gate GEMM -> cumsum -> {cvt(W), GEMM, shift(+RoPE)} x3
//           -> V transpose -> flash attention (decay term) -> out GEMM.
// ---------------------------------------------------------------------------

typedef __attribute__((ext_vector_type(8))) short  shortx8;
typedef __attribute__((ext_vector_type(4))) float  floatx4;

#define DEV __device__ __forceinline__

DEV unsigned short f2bf(float f) {                 // fp32 -> bf16 RNE
    unsigned int u = __builtin_bit_cast(unsigned int, f);
    u += 0x7FFFu + ((u >> 16) & 1u);
    return (unsigned short)(u >> 16);
}
DEV float bf2f(unsigned short s) {
    unsigned int u = ((unsigned int)s) << 16;
    return __builtin_bit_cast(float, u);
}
DEV void async16(void* lds, const void* g) {       // 16B global->LDS DMA (lds dest: wave-uniform base + lane*16)
    __builtin_amdgcn_global_load_lds(
        (const __attribute__((address_space(1))) unsigned int*)g,
        (__attribute__((address_space(3))) unsigned int*)lds, 16, 0, 0);
}

// ---------------------------------------------------------------------------
// fp32 -> bf16 conversion, 8 elems/thread
// ---------------------------------------------------------------------------
__global__ void cvt_bf16(const float* __restrict__ in, unsigned short* __restrict__ out, int n8) {
    int i = blockIdx.x * 256 + threadIdx.x;
    if (i >= n8) return;
    float4 u = ((const float4*)in)[2 * i];
    float4 v = ((const float4*)in)[2 * i + 1];
    shortx8 r;
    r[0] = (short)f2bf(u.x); r[1] = (short)f2bf(u.y); r[2] = (short)f2bf(u.z); r[3] = (short)f2bf(u.w);
    r[4] = (short)f2bf(v.x); r[5] = (short)f2bf(v.y); r[6] = (short)f2bf(v.z); r[7] = (short)f2bf(v.w);
    *(shortx8*)(out + (size_t)i * 8) = r;
}

// Wcat: rows 0-15 Wsq, 16-31 Wsk, 32-47 Wsv, 48-63 Wf, 64-127 zero. (128,2048) bf16
__global__ void build_wcat(const float* __restrict__ Wsq, const float* __restrict__ Wsk,
                           const float* __restrict__ Wsv, const float* __restrict__ Wf,
                           unsigned short* __restrict__ out) {
    int i = blockIdx.x * 256 + threadIdx.x;       // 32768 chunks of 8
    int c8 = i & 255;
    int row = i >> 8;
    const float* src = nullptr;
    if      (row < 16) src = Wsq + (size_t)row * 2048;
    else if (row < 32) src = Wsk + (size_t)(row - 16) * 2048;
    else if (row < 48) src = Wsv + (size_t)(row - 32) * 2048;
    else if (row < 64) src = Wf  + (size_t)(row - 48) * 2048;
    shortx8 r = (shortx8){0,0,0,0,0,0,0,0};
    if (src) {
#pragma unroll
        for (int q = 0; q < 8; ++q) r[q] = (short)f2bf(src[c8 * 8 + q]);
    }
    *(shortx8*)(out + (size_t)i * 8) = r;
}

// ---------------------------------------------------------------------------
// C(M,N) = A(M,K) @ B(N,K)^T , bf16 in, OutT out (float or bf16-as-ushort).
// m97 structure: 128x128 tile, BK=32, 4 waves (2x2 of 64x64), dbuf LDS,
// global_load_lds width 16.  M%128==0, N%128==0, K%32==0.
// ---------------------------------------------------------------------------
template <typename OutT>
__global__ __launch_bounds__(256)
void gemm_bt(const unsigned short* __restrict__ A, const unsigned short* __restrict__ B,
             OutT* __restrict__ C, int M, int N, int K) {
    __shared__ __align__(16) unsigned short As[2][128 * 32];
    __shared__ __align__(16) unsigned short Bs[2][128 * 32];
    const int tid  = threadIdx.x;
    const int lane = tid & 63;
    const int w    = tid >> 6;
    const int m0   = blockIdx.x * 128;
    const int n0   = blockIdx.y * 128;
    const int wr   = (w >> 1) * 64;
    const int wc   = (w & 1) * 64;
    const int l15  = lane & 15, lg = lane >> 4;
    const int nk   = K >> 5;
    const int c0   = w * 64 + lane;

    floatx4 acc[4][4];
#pragma unroll
    for (int i = 0; i < 4; ++i)
#pragma unroll
        for (int j = 0; j < 4; ++j) acc[i][j] = (floatx4){0.f, 0.f, 0.f, 0.f};

    // stage kt = 0 into buffer 0.  c = linear chunk id; row = c>>2, seg = c&3,
    // LDS elem offset = c*8  ->  row-major [128][32] (linear dest, m104-safe).
#pragma unroll
    for (int t = 0; t < 2; ++t) {
        int c = t * 256 + c0;
        int row = c >> 2, seg = c & 3;
        async16(&As[0][(t * 256 + w * 64) * 8], A + (size_t)(m0 + row) * K + seg * 8);
        async16(&Bs[0][(t * 256 + w * 64) * 8], B + (size_t)(n0 + row) * K + seg * 8);
    }
    int cur = 0;
    for (int kt = 0; kt < nk; ++kt) {
        __syncthreads();                           // drains vmcnt: buf 'cur' ready
        if (kt + 1 < nk) {
#pragma unroll
            for (int t = 0; t < 2; ++t) {
                int c = t * 256 + c0;
                int row = c >> 2, seg = c & 3;
                async16(&As[cur ^ 1][(t * 256 + w * 64) * 8],
                        A + (size_t)(m0 + row) * K + (kt + 1) * 32 + seg * 8);
                async16(&Bs[cur ^ 1][(t * 256 + w * 64) * 8],
                        B + (size_t)(n0 + row) * K + (kt + 1) * 32 + seg * 8);
            }
        }
        shortx8 af[4], bfr[4];
#pragma unroll
        for (int i = 0; i < 4; ++i) {
            af[i]  = *(const shortx8*)&As[cur][(wr + i * 16 + l15) * 32 + 8 * lg];
            bfr[i] = *(const shortx8*)&Bs[cur][(wc + i * 16 + l15) * 32 + 8 * lg];
        }
#pragma unroll
        for (int i = 0; i < 4; ++i)
#pragma unroll
            for (int j = 0; j < 4; ++j)
                acc[i][j] = __builtin_amdgcn_mfma_f32_16x16x32_bf16(af[i], bfr[j], acc[i][j], 0, 0, 0);
        cur ^= 1;
    }
    // epilogue: D row = 4*lg + r, col = l15  (m89-verified layout)
#pragma unroll
    for (int i = 0; i < 4; ++i)
#pragma unroll
        for (int j = 0; j < 4; ++j)
#pragma unroll
            for (int r = 0; r < 4; ++r) {
                int row = m0 + wr + i * 16 + 4 * lg + r;
                int col = n0 + wc + j * 16 + l15;
                float v = acc[i][j][r];
                if constexpr (sizeof(OutT) == 2) C[(size_t)row * N + col] = (OutT)f2bf(v);
                else                             C[(size_t)row * N + col] = v;
            }
}

// ---------------------------------------------------------------------------
// cum[b,h,t] = cumsum_t( log_sigmoid(glog[b,t,48+h] + bf[h]) ), fp32
// one block per (b,h), 256 thr x 8 elems, Hillis-Steele block scan.
// ---------------------------------------------------------------------------
__global__ void cumsum_logf(const float* __restrict__ glog, const float* __restrict__ bfv,
                            float* __restrict__ cum) {
    __shared__ float sums[256];
    const int bh = blockIdx.x, b = bh >> 4, h = bh & 15;
    const int tid = threadIdx.x;
    const float bias = bfv[h];
    float v[8];
    float s = 0.f;
#pragma unroll
    for (int i = 0; i < 8; ++i) {
        int t = tid * 8 + i;
        float z = glog[(size_t)(b * 2048 + t) * 128 + 48 + h] + bias;
        float lf = (z >= 0.f) ? -log1pf(__expf(-z)) : (z - log1pf(__expf(z)));
        s += lf;
        v[i] = s;
    }
    sums[tid] = s;
    __syncthreads();
    for (int off = 1; off < 256; off <<= 1) {
        float t = (tid >= off) ? sums[tid - off] : 0.f;
        __syncthreads();
        sums[tid] += t;
        __syncthreads();
    }
    float basep = sums[tid] - s;                   // exclusive prefix of thread totals
#pragma unroll
    for (int i = 0; i < 8; ++i)
        cum[(size_t)bh * 2048 + tid * 8 + i] = basep + v[i];
}

// ---------------------------------------------------------------------------
// shift-mix (y*(1-p) + y_prev*p, p per (b,t,h)) + optional RoPE; writes (B,H,T,D)
// thread: (b,t,h,j) j=0..7 handles d = j*8..j*8+7 and d+64 (rope pair halves).
// ---------------------------------------------------------------------------
template <bool ROPE>
__global__ void shift_rope(const unsigned short* __restrict__ Y, const float* __restrict__ glog,
                           int gcol, unsigned short* __restrict__ Out) {
    int gid = blockIdx.x * 256 + threadIdx.x;     // B*T*H*8 = 524288
    int j = gid & 7;
    int h = (gid >> 3) & 15;
    int t = (gid >> 7) & 2047;
    int b = gid >> 18;
    const unsigned short* yp = Y + (size_t)(b * 2048 + t) * 2048 + h * 128;
    float z  = glog[(size_t)(b * 2048 + t) * 128 + gcol + h];
    float pg = 1.f / (1.f + __expf(-z));
    shortx8 a1 = *(const shortx8*)(yp + j * 8);
    shortx8 a2 = *(const shortx8*)(yp + 64 + j * 8);
    shortx8 b1 = (shortx8){0,0,0,0,0,0,0,0}, b2 = b1;
    if (t > 0) {
        b1 = *(const shortx8*)(yp - 2048 + j * 8);
        b2 = *(const shortx8*)(yp - 2048 + 64 + j * 8);
    }
    shortx8 o1, o2;
    const float kf = 13.287712379549449f / 64.f;  // log2(10000)/64
#pragma unroll
    for (int i = 0; i < 8; ++i) {
        float m1 = bf2f((unsigned short)a1[i]) * (1.f - pg) + bf2f((unsigned short)b1[i]) * pg;
        float m2 = bf2f((unsigned short)a2[i]) * (1.f - pg) + bf2f((unsigned short)b2[i]) * pg;
        float r1, r2;
        if (ROPE) {
            int d = j * 8 + i;
            float inv = exp2f(-(float)d * kf);    // 10000^(-d/64)
            float ang = (float)t * inv;
            float sv, cv;
            sincosf(ang, &sv, &cv);               // accurate version: angles up to 2048 rad
            r1 =  m1 * cv + m2 * sv;
            r2 = -m1 * sv + m2 * cv;
        } else { r1 = m1; r2 = m2; }
        o1[i] = (short)f2bf(r1);
        o2[i] = (short)f2bf(r2);
    }
    unsigned short* op = Out + (size_t)((b * 16 + h) * 2048 + t) * 128;
    *(shortx8*)(op + j * 8)      = o1;
    *(shortx8*)(op + 64 + j * 8) = o2;
}

// (BH,T,D) -> (BH,D,T) bf16 transpose, 32x32 LDS tiles
__global__ void transpose_v(const unsigned short* __restrict__ V, unsigned short* __restrict__ Vt) {
    __shared__ unsigned short tile[32][33];
    const int bh = blockIdx.z;
    const int t0 = blockIdx.x * 32, d0 = blockIdx.y * 32;
    const int tx = threadIdx.x, ty = threadIdx.y;  // (32,8)
#pragma unroll
    for (int i = 0; i < 4; ++i) {
        int row = ty + i * 8;
        tile[row][tx] = V[(size_t)(bh * 2048 + t0 + row) * 128 + d0 + tx];
    }
    __syncthreads();
#pragma unroll
    for (int i = 0; i < 4; ++i) {
        int drow = ty + i * 8;
        Vt[(size_t)(bh * 128 + d0 + drow) * 2048 + t0 + tx] = tile[tx][drow];
    }
}

// ---------------------------------------------------------------------------
// Flash attention with additive decay:  s = qk/sqrt(D) + cum_t - cum_s, causal.
// grid (T/64, B*H); 4 waves x 16 q-rows.  Q frags in regs; K and Vt frags read
// from global (L1/L2-resident; Common-mistake #7: don't stage what caches);
// P lane-transposed through per-wave padded LDS slab (no barrier needed).
// Output written bf16 token-major (B*T, 2048) at col h*128+d.
// ---------------------------------------------------------------------------
__global__ __launch_bounds__(256)
void flash_fwd(const unsigned short* __restrict__ Q, const unsigned short* __restrict__ Km,
               const unsigned short* __restrict__ Vt, const float* __restrict__ cum,
               unsigned short* __restrict__ O) {
    __shared__ __align__(16) unsigned short Plds[4][16][72];   // pad 72: bank-step 4
    const int tid = threadIdx.x, lane = tid & 63, w = tid >> 6;
    const int l15 = lane & 15, lg = lane >> 4;
    const int bh = blockIdx.y, b = bh >> 4, h = bh & 15;
    const int q0 = blockIdx.x * 64;
    const int qr = q0 + w * 16;
    const size_t base = (size_t)bh * (2048 * 128);
    const float isd = 0.08838834764831845f;        // 1/sqrt(128)

    shortx8 aq[4];
#pragma unroll
    for (int kk = 0; kk < 4; ++kk)
        aq[kk] = *(const shortx8*)(Q + base + (size_t)(qr + l15) * 128 + kk * 32 + 8 * lg);

    float cum_t[4];
#pragma unroll
    for (int r = 0; r < 4; ++r) cum_t[r] = cum[bh * 2048 + qr + 4 * lg + r];

    floatx4 oacc[8];
#pragma unroll
    for (int d = 0; d < 8; ++d) oacc[d] = (floatx4){0.f, 0.f, 0.f, 0.f};
    float m[4]  = {-1e30f, -1e30f, -1e30f, -1e30f};
    float ls[4] = {0.f, 0.f, 0.f, 0.f};

    const int ntiles = blockIdx.x + 1;
    for (int kt = 0; kt < ntiles; ++kt) {
        const int s0 = kt * 64;
        floatx4 sacc[4];
#pragma unroll
        for (int sf = 0; sf < 4; ++sf) sacc[sf] = (floatx4){0.f, 0.f, 0.f, 0.f};
#pragma unroll
        for (int sf = 0; sf < 4; ++sf)
#pragma unroll
            for (int kk = 0; kk < 4; ++kk) {
                shortx8 bk = *(const shortx8*)(Km + base + (size_t)(s0 + sf * 16 + l15) * 128 + kk * 32 + 8 * lg);
                sacc[sf] = __builtin_amdgcn_mfma_f32_16x16x32_bf16(aq[kk], bk, sacc[sf], 0, 0, 0);
            }
        float cs[4];
#pragma unroll
        for (int sf = 0; sf < 4; ++sf) cs[sf] = cum[bh * 2048 + s0 + sf * 16 + l15];

        float p[4][4];
        float tmax[4] = {-1e30f, -1e30f, -1e30f, -1e30f};
        const bool lastt = (kt == ntiles - 1);
#pragma unroll
        for (int sf = 0; sf < 4; ++sf)
#pragma unroll
            for (int r = 0; r < 4; ++r) {
                float sv = sacc[sf][r] * isd + cum_t[r] - cs[sf];
                if (lastt) {
                    int trow = qr + 4 * lg + r;
                    int scol = s0 + sf * 16 + l15;
                    if (scol > trow) sv = -1e30f;
                }
                p[sf][r] = sv;
                tmax[r] = fmaxf(tmax[r], sv);
            }
#pragma unroll
        for (int r = 0; r < 4; ++r) {
            tmax[r] = fmaxf(tmax[r], __shfl_xor(tmax[r], 1));
            tmax[r] = fmaxf(tmax[r], __shfl_xor(tmax[r], 2));
            tmax[r] = fmaxf(tmax[r], __shfl_xor(tmax[r], 4));
            tmax[r] = fmaxf(tmax[r], __shfl_xor(tmax[r], 8));
        }
        float scl[4];
#pragma unroll
        for (int r = 0; r < 4; ++r) {
            float mn = fmaxf(m[r], tmax[r]);
            scl[r] = __expf(m[r] - mn);
            m[r] = mn;
        }
        float rs[4] = {0.f, 0.f, 0.f, 0.f};
#pragma unroll
        for (int sf = 0; sf < 4; ++sf)
#pragma unroll
            for (int r = 0; r < 4; ++r) {
                float e = __expf(p[sf][r] - m[r]);
                p[sf][r] = e;
                rs[r] += e;
            }
#pragma unroll
        for (int r = 0; r < 4; ++r) {
            rs[r] += __shfl_xor(rs[r], 1);
            rs[r] += __shfl_xor(rs[r], 2);
            rs[r] += __shfl_xor(rs[r], 4);
            rs[r] += __shfl_xor(rs[r], 8);
            ls[r] = ls[r] * scl[r] + rs[r];
        }
#pragma unroll
        for (int d = 0; d < 8; ++d)
#pragma unroll
            for (int r = 0; r < 4; ++r) oacc[d][r] *= scl[r];

        // P: D-layout (row=4lg+r) -> LDS -> A-layout (row=l15). per-wave slab, in-order DS.
#pragma unroll
        for (int sf = 0; sf < 4; ++sf)
#pragma unroll
            for (int r = 0; r < 4; ++r)
                Plds[w][4 * lg + r][sf * 16 + l15] = f2bf(p[sf][r]);
#pragma unroll
        for (int kk2 = 0; kk2 < 2; ++kk2) {
            shortx8 pa = *(const shortx8*)&Plds[w][l15][kk2 * 32 + 8 * lg];
#pragma unroll
            for (int d = 0; d < 8; ++d) {
                shortx8 bv = *(const shortx8*)(Vt + (size_t)(bh * 128 + d * 16 + l15) * 2048 + s0 + kk2 * 32 + 8 * lg);
                oacc[d] = __builtin_amdgcn_mfma_f32_16x16x32_bf16(pa, bv, oacc[d], 0, 0, 0);
            }
        }
    }
#pragma unroll
    for (int r = 0; r < 4; ++r) {
        float inv = 1.f / ls[r];
        int trow = qr + 4 * lg + r;
        size_t ob = (size_t)(b * 2048 + trow) * 2048 + h * 128;
#pragma unroll
        for (int d = 0; d < 8; ++d)
            O[ob + d * 16 + l15] = f2bf(oacc[d][r] * inv);
    }
}

// ---------------------------------------------------------------------------
extern "C" void kernel_launch(void* const* d_in, const int* in_sizes, int n_in,
                              void* d_out, int out_size, void* d_ws, size_t ws_size,
                              hipStream_t stream) {
    const float* x   = (const float*)d_in[0];
    const float* Wq  = (const float*)d_in[1];
    const float* Wsq = (const float*)d_in[2];
    const float* Wk  = (const float*)d_in[3];
    const float* Wsk = (const float*)d_in[4];
    const float* Wv  = (const float*)d_in[5];
    const float* Wsv = (const float*)d_in[6];
    const float* Wf  = (const float*)d_in[7];
    const float* bfv = (const float*)d_in[8];
    const float* Wo  = (const float*)d_in[9];
    float* out = (float*)d_out;
    char* ws = (char*)d_ws;

    unsigned short* xb   = (unsigned short*)(ws + 0);          // 16 MB  x bf16 (4096,2048)
    unsigned short* Wb   = (unsigned short*)(ws + 16777216);   //  8 MB  current weight bf16
    unsigned short* wcat = (unsigned short*)(ws + 25165824);   // 0.5 MB gate weights (128,2048)
    float*          glog = (float*)(ws + 25690112);            //  2 MB  gate logits (4096,128)
    float*          cum  = (float*)(ws + 27787264);            // .25 MB cum (BH,2048)
    unsigned short* ybuf = (unsigned short*)(ws + 28049408);   // 16 MB  y / o scratch (4096,2048)
    unsigned short* qbuf = (unsigned short*)(ws + 44826624);   // 16 MB  q (BH,T,D)
    unsigned short* kbuf = (unsigned short*)(ws + 61603840);   // 16 MB  k (BH,T,D)
    unsigned short* vbuf = (unsigned short*)(ws + 78381056);   // 16 MB  v (BH,T,D)
    unsigned short* vt   = (unsigned short*)(ws + 95158272);   // 16 MB  v^T (BH,D,T)   tot 107 MB

    cvt_bf16<<<4096, 256, 0, stream>>>(x, xb, 1048576);
    build_wcat<<<128, 256, 0, stream>>>(Wsq, Wsk, Wsv, Wf, wcat);
    gemm_bt<float><<<dim3(32, 1), 256, 0, stream>>>(xb, wcat, glog, 4096, 128, 2048);
    cumsum_logf<<<32, 256, 0, stream>>>(glog, bfv, cum);

    cvt_bf16<<<2048, 256, 0, stream>>>(Wq, Wb, 524288);
    gemm_bt<unsigned short><<<dim3(32, 16), 256, 0, stream>>>(xb, Wb, ybuf, 4096, 2048, 2048);
    shift_rope<true><<<2048, 256, 0, stream>>>(ybuf, glog, 0, qbuf);

    cvt_bf16<<<2048, 256, 0, stream>>>(Wk, Wb, 524288);
    gemm_bt<unsigned short><<<dim3(32, 16), 256, 0, stream>>>(xb, Wb, ybuf, 4096, 2048, 2048);
    shift_rope<true><<<2048, 256, 0, stream>>>(ybuf, glog, 16, kbuf);

    cvt_bf16<<<2048, 256, 0, stream>>>(Wv, Wb, 524288);
    gemm_bt<unsigned short><<<dim3(32, 16), 256, 0, stream>>>(xb, Wb, ybuf, 4096, 2048, 2048);
    shift_rope<false><<<2048, 256, 0, stream>>>(ybuf, glog, 32, vbuf);
    transpose_v<<<dim3(64, 4, 32), dim3(32, 8), 0, stream>>>(vbuf, vt);

    flash_fwd<<<dim3(32, 32), 256, 0, stream>>>(qbuf, kbuf, vt, cum, ybuf);

    cvt_bf16<<<2048, 256, 0, stream>>>(Wo, Wb, 524288);
    gemm_bt<float><<<dim3(32, 16), 256, 0, stream>>>(ybuf, Wb, out, 4096, 2048, 2048);
}

// Round 4
// 580.358 us; speedup vs baseline: 1.9227x; 1.9227x over previous
//
#include <hip/hip_runtime.h>
#include <math.h>

// ---------------------------------------------------------------------------
// ForgettingAttentionLayer, MI355X bf16-MFMA pipeline.  B=2 T=2048 C=2048 H=16 D=128.
// R3: flash_fwd rewritten (LDS-staged shared K/V, dbuf 2-phase, swizzled, QBLK=128,
//     diagonal remap); QKV projections fused into one N=6144 GEMM (ws-gated).
// ---------------------------------------------------------------------------

typedef __attribute__((ext_vector_type(8))) short  shortx8;
typedef __attribute__((ext_vector_type(4))) float  floatx4;

#define DEV __device__ __forceinline__

DEV unsigned short f2bf(float f) {                 // fp32 -> bf16 RNE
    unsigned int u = __builtin_bit_cast(unsigned int, f);
    u += 0x7FFFu + ((u >> 16) & 1u);
    return (unsigned short)(u >> 16);
}
DEV float bf2f(unsigned short s) {
    unsigned int u = ((unsigned int)s) << 16;
    return __builtin_bit_cast(float, u);
}
DEV void async16(void* lds, const void* g) {       // 16B global->LDS DMA
    __builtin_amdgcn_global_load_lds(
        (const __attribute__((address_space(1))) unsigned int*)g,
        (__attribute__((address_space(3))) unsigned int*)lds, 16, 0, 0);
}

// ---------------------------------------------------------------------------
__global__ void cvt_bf16(const float* __restrict__ in, unsigned short* __restrict__ out, int n8) {
    int i = blockIdx.x * 256 + threadIdx.x;
    if (i >= n8) return;
    float4 u = ((const float4*)in)[2 * i];
    float4 v = ((const float4*)in)[2 * i + 1];
    shortx8 r;
    r[0] = (short)f2bf(u.x); r[1] = (short)f2bf(u.y); r[2] = (short)f2bf(u.z); r[3] = (short)f2bf(u.w);
    r[4] = (short)f2bf(v.x); r[5] = (short)f2bf(v.y); r[6] = (short)f2bf(v.z); r[7] = (short)f2bf(v.w);
    *(shortx8*)(out + (size_t)i * 8) = r;
}

// Wcat: rows 0-15 Wsq, 16-31 Wsk, 32-47 Wsv, 48-63 Wf, 64-127 zero. (128,2048) bf16
__global__ void build_wcat(const float* __restrict__ Wsq, const float* __restrict__ Wsk,
                           const float* __restrict__ Wsv, const float* __restrict__ Wf,
                           unsigned short* __restrict__ out) {
    int i = blockIdx.x * 256 + threadIdx.x;
    int c8 = i & 255;
    int row = i >> 8;
    const float* src = nullptr;
    if      (row < 16) src = Wsq + (size_t)row * 2048;
    else if (row < 32) src = Wsk + (size_t)(row - 16) * 2048;
    else if (row < 48) src = Wsv + (size_t)(row - 32) * 2048;
    else if (row < 64) src = Wf  + (size_t)(row - 48) * 2048;
    shortx8 r = (shortx8){0,0,0,0,0,0,0,0};
    if (src) {
#pragma unroll
        for (int q = 0; q < 8; ++q) r[q] = (short)f2bf(src[c8 * 8 + q]);
    }
    *(shortx8*)(out + (size_t)i * 8) = r;
}

// ---------------------------------------------------------------------------
// C(M,N) = A(M,K) @ B(N,K)^T ; m97 structure (128x128 tile, BK=32, 4 waves, dbuf).
// ---------------------------------------------------------------------------
template <typename OutT>
__global__ __launch_bounds__(256)
void gemm_bt(const unsigned short* __restrict__ A, const unsigned short* __restrict__ B,
             OutT* __restrict__ C, int M, int N, int K) {
    __shared__ __align__(16) unsigned short As[2][128 * 32];
    __shared__ __align__(16) unsigned short Bs[2][128 * 32];
    const int tid  = threadIdx.x;
    const int lane = tid & 63;
    const int w    = tid >> 6;
    const int m0   = blockIdx.x * 128;
    const int n0   = blockIdx.y * 128;
    const int wr   = (w >> 1) * 64;
    const int wc   = (w & 1) * 64;
    const int l15  = lane & 15, lg = lane >> 4;
    const int nk   = K >> 5;
    const int c0   = w * 64 + lane;

    floatx4 acc[4][4];
#pragma unroll
    for (int i = 0; i < 4; ++i)
#pragma unroll
        for (int j = 0; j < 4; ++j) acc[i][j] = (floatx4){0.f, 0.f, 0.f, 0.f};

#pragma unroll
    for (int t = 0; t < 2; ++t) {
        int c = t * 256 + c0;
        int row = c >> 2, seg = c & 3;
        async16(&As[0][(t * 256 + w * 64) * 8], A + (size_t)(m0 + row) * K + seg * 8);
        async16(&Bs[0][(t * 256 + w * 64) * 8], B + (size_t)(n0 + row) * K + seg * 8);
    }
    int cur = 0;
    for (int kt = 0; kt < nk; ++kt) {
        __syncthreads();
        if (kt + 1 < nk) {
#pragma unroll
            for (int t = 0; t < 2; ++t) {
                int c = t * 256 + c0;
                int row = c >> 2, seg = c & 3;
                async16(&As[cur ^ 1][(t * 256 + w * 64) * 8],
                        A + (size_t)(m0 + row) * K + (kt + 1) * 32 + seg * 8);
                async16(&Bs[cur ^ 1][(t * 256 + w * 64) * 8],
                        B + (size_t)(n0 + row) * K + (kt + 1) * 32 + seg * 8);
            }
        }
        shortx8 af[4], bfr[4];
#pragma unroll
        for (int i = 0; i < 4; ++i) {
            af[i]  = *(const shortx8*)&As[cur][(wr + i * 16 + l15) * 32 + 8 * lg];
            bfr[i] = *(const shortx8*)&Bs[cur][(wc + i * 16 + l15) * 32 + 8 * lg];
        }
#pragma unroll
        for (int i = 0; i < 4; ++i)
#pragma unroll
            for (int j = 0; j < 4; ++j)
                acc[i][j] = __builtin_amdgcn_mfma_f32_16x16x32_bf16(af[i], bfr[j], acc[i][j], 0, 0, 0);
        cur ^= 1;
    }
#pragma unroll
    for (int i = 0; i < 4; ++i)
#pragma unroll
        for (int j = 0; j < 4; ++j)
#pragma unroll
            for (int r = 0; r < 4; ++r) {
                int row = m0 + wr + i * 16 + 4 * lg + r;
                int col = n0 + wc + j * 16 + l15;
                float v = acc[i][j][r];
                if constexpr (sizeof(OutT) == 2) C[(size_t)row * N + col] = (OutT)f2bf(v);
                else                             C[(size_t)row * N + col] = v;
            }
}

// ---------------------------------------------------------------------------
__global__ void cumsum_logf(const float* __restrict__ glog, const float* __restrict__ bfv,
                            float* __restrict__ cum) {
    __shared__ float sums[256];
    const int bh = blockIdx.x, b = bh >> 4, h = bh & 15;
    const int tid = threadIdx.x;
    const float bias = bfv[h];
    float v[8];
    float s = 0.f;
#pragma unroll
    for (int i = 0; i < 8; ++i) {
        int t = tid * 8 + i;
        float z = glog[(size_t)(b * 2048 + t) * 128 + 48 + h] + bias;
        float lf = (z >= 0.f) ? -log1pf(__expf(-z)) : (z - log1pf(__expf(z)));
        s += lf;
        v[i] = s;
    }
    sums[tid] = s;
    __syncthreads();
    for (int off = 1; off < 256; off <<= 1) {
        float t = (tid >= off) ? sums[tid - off] : 0.f;
        __syncthreads();
        sums[tid] += t;
        __syncthreads();
    }
    float basep = sums[tid] - s;
#pragma unroll
    for (int i = 0; i < 8; ++i)
        cum[(size_t)bh * 2048 + tid * 8 + i] = basep + v[i];
}

// ---------------------------------------------------------------------------
// shift-mix + optional RoPE; reads Y (B*T, ldY) at col yoff+h*128; writes (B,H,T,D).
// ---------------------------------------------------------------------------
template <bool ROPE>
__global__ void shift_rope(const unsigned short* __restrict__ Y, int ldY, int yoff,
                           const float* __restrict__ glog, int gcol,
                           unsigned short* __restrict__ Out) {
    int gid = blockIdx.x * 256 + threadIdx.x;
    int j = gid & 7;
    int h = (gid >> 3) & 15;
    int t = (gid >> 7) & 2047;
    int b = gid >> 18;
    const unsigned short* yp = Y + (size_t)(b * 2048 + t) * ldY + yoff + h * 128;
    float z  = glog[(size_t)(b * 2048 + t) * 128 + gcol + h];
    float pg = 1.f / (1.f + __expf(-z));
    shortx8 a1 = *(const shortx8*)(yp + j * 8);
    shortx8 a2 = *(const shortx8*)(yp + 64 + j * 8);
    shortx8 b1 = (shortx8){0,0,0,0,0,0,0,0}, b2 = b1;
    if (t > 0) {
        b1 = *(const shortx8*)(yp - ldY + j * 8);
        b2 = *(const shortx8*)(yp - ldY + 64 + j * 8);
    }
    shortx8 o1, o2;
    const float kf = 13.287712379549449f / 64.f;  // log2(10000)/64
#pragma unroll
    for (int i = 0; i < 8; ++i) {
        float m1 = bf2f((unsigned short)a1[i]) * (1.f - pg) + bf2f((unsigned short)b1[i]) * pg;
        float m2 = bf2f((unsigned short)a2[i]) * (1.f - pg) + bf2f((unsigned short)b2[i]) * pg;
        float r1, r2;
        if (ROPE) {
            int d = j * 8 + i;
            float inv = exp2f(-(float)d * kf);
            float ang = (float)t * inv;
            float sv, cv;
            sincosf(ang, &sv, &cv);
            r1 =  m1 * cv + m2 * sv;
            r2 = -m1 * sv + m2 * cv;
        } else { r1 = m1; r2 = m2; }
        o1[i] = (short)f2bf(r1);
        o2[i] = (short)f2bf(r2);
    }
    unsigned short* op = Out + (size_t)((b * 16 + h) * 2048 + t) * 128;
    *(shortx8*)(op + j * 8)      = o1;
    *(shortx8*)(op + 64 + j * 8) = o2;
}

// (BH,T,D) -> (BH,D,T) bf16 transpose
__global__ void transpose_v(const unsigned short* __restrict__ V, unsigned short* __restrict__ Vt) {
    __shared__ unsigned short tile[32][33];
    const int bh = blockIdx.z;
    const int t0 = blockIdx.x * 32, d0 = blockIdx.y * 32;
    const int tx = threadIdx.x, ty = threadIdx.y;
#pragma unroll
    for (int i = 0; i < 4; ++i) {
        int row = ty + i * 8;
        tile[row][tx] = V[(size_t)(bh * 2048 + t0 + row) * 128 + d0 + tx];
    }
    __syncthreads();
#pragma unroll
    for (int i = 0; i < 4; ++i) {
        int drow = ty + i * 8;
        Vt[(size_t)(bh * 128 + d0 + drow) * 2048 + t0 + tx] = tile[tx][drow];
    }
}

// ---------------------------------------------------------------------------
// flash v2: QBLK=128 (8 waves x 16 q-rows), KVBLK=32, K/V cooperatively staged
// to LDS via global_load_lds (linear dest + inverse-swizzled global source,
// XOR chunk swizzle c^=r&7 -> 2-way reads, rule #21), double-buffered 2-phase
// (issue next DMA -> compute current -> barrier drains vmcnt).  Diagonal remap
// qx=(bx+by)&15 balances causal depth per CU.  grid (16, BH), 512 thr.
// ---------------------------------------------------------------------------
__global__ __launch_bounds__(512)
void flash_fwd(const unsigned short* __restrict__ Q, const unsigned short* __restrict__ Km,
               const unsigned short* __restrict__ Vt, const float* __restrict__ cum,
               unsigned short* __restrict__ O) {
    __shared__ __align__(16) unsigned short Ks[2][32 * 128];   // [time 32][d 128]
    __shared__ __align__(16) unsigned short Vs[2][64 * 64];    // packed: row=d>>1, 2 d-rows/128B
    __shared__ __align__(16) unsigned short Plds[8][16][40];   // per-wave P slab (16B-aligned rows)
    const int tid = threadIdx.x, lane = tid & 63, w = tid >> 6;
    const int l15 = lane & 15, lg = lane >> 4;
    const int bh = blockIdx.y, b = bh >> 4, h = bh & 15;
    const int qx = (blockIdx.x + bh) & 15;
    const int q0 = qx * 128;
    const int qr = q0 + w * 16;
    const size_t base = (size_t)bh * (2048 * 128);
    const float isd = 0.08838834764831845f;        // 1/sqrt(128)
    const int ntiles = 4 * qx + 4;
    const int myn0 = ((qr + 15) >> 5) + 1;
    const int myn = myn0 < ntiles ? myn0 : ntiles; // this wave's causal frontier

    // --- staging constants (chunk = 16B): LDS[r][c] <- G[r][c ^ (r&7)]
    const int ik = w * 64 + lane;                  // K chunk 0..511: r=ik>>4, c=ik&15
    const int kr = ik >> 4, kc = ik & 15;
    const unsigned short* ksrc = Km + base + (size_t)kr * 128 + ((kc ^ (kr & 7)) * 8);
    const int vr = ik >> 3, vc = ik & 7;           // V chunk 0..511: packed row vr, chunk vc
    const int vcc = vc ^ (vr & 7);
    const unsigned short* vsrc = Vt + (size_t)(bh * 128 + 2 * vr + (vcc >> 2)) * 2048 + (vcc & 3) * 8;

    // --- ds_read constants
    const int kx = l15 & 7;                        // K-frag row-xor
    const int vconst = ((l15 >> 1) * 64) + ((((l15 & 1) * 4 + lg) ^ ((l15 >> 1) & 7)) * 8);

    shortx8 aq[4];
#pragma unroll
    for (int kk = 0; kk < 4; ++kk)
        aq[kk] = *(const shortx8*)(Q + base + (size_t)(qr + l15) * 128 + kk * 32 + 8 * lg);

    float cum_t[4];
#pragma unroll
    for (int r = 0; r < 4; ++r) cum_t[r] = cum[bh * 2048 + qr + 4 * lg + r];

    floatx4 oacc[8];
#pragma unroll
    for (int d = 0; d < 8; ++d) oacc[d] = (floatx4){0.f, 0.f, 0.f, 0.f};
    float m[4]  = {-1e30f, -1e30f, -1e30f, -1e30f};
    float ls[4] = {0.f, 0.f, 0.f, 0.f};

    // prologue: stage tile 0 (each wave stages 1/8 of K and V tiles)
    async16(&Ks[0][ik * 8], ksrc);
    async16(&Vs[0][ik * 8], vsrc);
    __syncthreads();                               // compiler drains vmcnt before barrier

    int cur = 0;
    for (int kt = 0; kt < ntiles; ++kt) {
        const int s0 = kt * 32;
        if (kt + 1 < ntiles) {                     // issue next-tile DMA first (overlaps compute)
            async16(&Ks[cur ^ 1][ik * 8], ksrc + (size_t)(kt + 1) * 32 * 128);
            async16(&Vs[cur ^ 1][ik * 8], vsrc + (kt + 1) * 32);
        }
        if (kt < myn) {                            // wave-uniform causal skip
            // QK^T from swizzled Ks
            floatx4 sacc[2];
            sacc[0] = (floatx4){0.f, 0.f, 0.f, 0.f};
            sacc[1] = (floatx4){0.f, 0.f, 0.f, 0.f};
#pragma unroll
            for (int sf = 0; sf < 2; ++sf)
#pragma unroll
                for (int kk = 0; kk < 4; ++kk) {
                    shortx8 bk = *(const shortx8*)&Ks[cur][(sf * 16 + l15) * 128 + (((kk * 4 + lg) ^ kx) * 8)];
                    sacc[sf] = __builtin_amdgcn_mfma_f32_16x16x32_bf16(aq[kk], bk, sacc[sf], 0, 0, 0);
                }
            float cs[2];
#pragma unroll
            for (int sf = 0; sf < 2; ++sf) cs[sf] = cum[bh * 2048 + s0 + sf * 16 + l15];

            float p[2][4];
            float tmax[4] = {-1e30f, -1e30f, -1e30f, -1e30f};
            const bool maskt = (s0 + 31 > qr);
#pragma unroll
            for (int sf = 0; sf < 2; ++sf)
#pragma unroll
                for (int r = 0; r < 4; ++r) {
                    float sv = sacc[sf][r] * isd + cum_t[r] - cs[sf];
                    if (maskt) {
                        int trow = qr + 4 * lg + r;
                        int scol = s0 + sf * 16 + l15;
                        if (scol > trow) sv = -1e30f;
                    }
                    p[sf][r] = sv;
                    tmax[r] = fmaxf(tmax[r], sv);
                }
#pragma unroll
            for (int r = 0; r < 4; ++r) {
                tmax[r] = fmaxf(tmax[r], __shfl_xor(tmax[r], 1));
                tmax[r] = fmaxf(tmax[r], __shfl_xor(tmax[r], 2));
                tmax[r] = fmaxf(tmax[r], __shfl_xor(tmax[r], 4));
                tmax[r] = fmaxf(tmax[r], __shfl_xor(tmax[r], 8));
            }
            float scl[4];
#pragma unroll
            for (int r = 0; r < 4; ++r) {
                float mn = fmaxf(m[r], tmax[r]);
                scl[r] = __expf(m[r] - mn);
                m[r] = mn;
            }
            float rs[4] = {0.f, 0.f, 0.f, 0.f};
#pragma unroll
            for (int sf = 0; sf < 2; ++sf)
#pragma unroll
                for (int r = 0; r < 4; ++r) {
                    float e = __expf(p[sf][r] - m[r]);
                    p[sf][r] = e;
                    rs[r] += e;
                }
#pragma unroll
            for (int r = 0; r < 4; ++r) {
                rs[r] += __shfl_xor(rs[r], 1);
                rs[r] += __shfl_xor(rs[r], 2);
                rs[r] += __shfl_xor(rs[r], 4);
                rs[r] += __shfl_xor(rs[r], 8);
                ls[r] = ls[r] * scl[r] + rs[r];
            }
#pragma unroll
            for (int d = 0; d < 8; ++d)
#pragma unroll
                for (int r = 0; r < 4; ++r) oacc[d][r] *= scl[r];

            // P: D-layout -> per-wave LDS slab -> A-layout (in-order DS within wave)
#pragma unroll
            for (int sf = 0; sf < 2; ++sf)
#pragma unroll
                for (int r = 0; r < 4; ++r)
                    Plds[w][4 * lg + r][sf * 16 + l15] = f2bf(p[sf][r]);
            shortx8 pa = *(const shortx8*)&Plds[w][l15][8 * lg];
            // PV from packed swizzled Vs
#pragma unroll
            for (int d = 0; d < 8; ++d) {
                shortx8 bv = *(const shortx8*)&Vs[cur][d * 512 + vconst];
                oacc[d] = __builtin_amdgcn_mfma_f32_16x16x32_bf16(pa, bv, oacc[d], 0, 0, 0);
            }
        }
        __syncthreads();                           // drains next-tile DMA + publishes buffer
        cur ^= 1;
    }
#pragma unroll
    for (int r = 0; r < 4; ++r) {
        float inv = 1.f / ls[r];
        int trow = qr + 4 * lg + r;
        size_t ob = (size_t)(b * 2048 + trow) * 2048 + h * 128;
#pragma unroll
        for (int d = 0; d < 8; ++d)
            O[ob + d * 16 + l15] = f2bf(oacc[d][r] * inv);
    }
}

// ---------------------------------------------------------------------------
extern "C" void kernel_launch(void* const* d_in, const int* in_sizes, int n_in,
                              void* d_out, int out_size, void* d_ws, size_t ws_size,
                              hipStream_t stream) {
    const float* x   = (const float*)d_in[0];
    const float* Wq  = (const float*)d_in[1];
    const float* Wsq = (const float*)d_in[2];
    const float* Wk  = (const float*)d_in[3];
    const float* Wsk = (const float*)d_in[4];
    const float* Wv  = (const float*)d_in[5];
    const float* Wsv = (const float*)d_in[6];
    const float* Wf  = (const float*)d_in[7];
    const float* bfv = (const float*)d_in[8];
    const float* Wo  = (const float*)d_in[9];
    float* out = (float*)d_out;
    char* ws = (char*)d_ws;

    if (ws_size >= 145489920ull) {
        // ---- fused-QKV path (needs 138.8 MB) ----
        unsigned short* xb    = (unsigned short*)(ws + 0);           // 16 MB; later: flash out
        unsigned short* Wb3   = (unsigned short*)(ws + 16777216);    // 24 MB  Wq|Wk|Wv bf16; later Wo
        unsigned short* wcat  = (unsigned short*)(ws + 41943040);    // 0.5 MB
        float*          glog  = (float*)(ws + 42467328);             // 2 MB
        float*          cum   = (float*)(ws + 44564480);             // .25 MB
        unsigned short* qbuf  = (unsigned short*)(ws + 44826624);    // 16 MB
        unsigned short* kbuf  = (unsigned short*)(ws + 61603840);    // 16 MB
        unsigned short* vbuf  = (unsigned short*)(ws + 78381056);    // 16 MB
        unsigned short* ybuf3 = (unsigned short*)(ws + 95158272);    // 48 MB (4096,6144)
        unsigned short* vt    = ybuf3;                               // reuse after shifts

        cvt_bf16<<<4096, 256, 0, stream>>>(x, xb, 1048576);
        build_wcat<<<128, 256, 0, stream>>>(Wsq, Wsk, Wsv, Wf, wcat);
        gemm_bt<float><<<dim3(32, 1), 256, 0, stream>>>(xb, wcat, glog, 4096, 128, 2048);
        cumsum_logf<<<32, 256, 0, stream>>>(glog, bfv, cum);

        cvt_bf16<<<2048, 256, 0, stream>>>(Wq, Wb3, 524288);
        cvt_bf16<<<2048, 256, 0, stream>>>(Wk, Wb3 + 4194304, 524288);
        cvt_bf16<<<2048, 256, 0, stream>>>(Wv, Wb3 + 8388608, 524288);
        gemm_bt<unsigned short><<<dim3(32, 48), 256, 0, stream>>>(xb, Wb3, ybuf3, 4096, 6144, 2048);

        shift_rope<true><<<2048, 256, 0, stream>>>(ybuf3, 6144, 0, glog, 0, qbuf);
        shift_rope<true><<<2048, 256, 0, stream>>>(ybuf3, 6144, 2048, glog, 16, kbuf);
        shift_rope<false><<<2048, 256, 0, stream>>>(ybuf3, 6144, 4096, glog, 32, vbuf);
        transpose_v<<<dim3(64, 4, 32), dim3(32, 8), 0, stream>>>(vbuf, vt);

        flash_fwd<<<dim3(16, 32), 512, 0, stream>>>(qbuf, kbuf, vt, cum, xb);

        cvt_bf16<<<2048, 256, 0, stream>>>(Wo, Wb3, 524288);
        gemm_bt<float><<<dim3(32, 16), 256, 0, stream>>>(xb, Wb3, out, 4096, 2048, 2048);
    } else {
        // ---- fallback: validated v1 structure + new flash (107 MB) ----
        unsigned short* xb   = (unsigned short*)(ws + 0);
        unsigned short* Wb   = (unsigned short*)(ws + 16777216);
        unsigned short* wcat = (unsigned short*)(ws + 25165824);
        float*          glog = (float*)(ws + 25690112);
        float*          cum  = (float*)(ws + 27787264);
        unsigned short* ybuf = (unsigned short*)(ws + 28049408);
        unsigned short* qbuf = (unsigned short*)(ws + 44826624);
        unsigned short* kbuf = (unsigned short*)(ws + 61603840);
        unsigned short* vbuf = (unsigned short*)(ws + 78381056);
        unsigned short* vt   = (unsigned short*)(ws + 95158272);

        cvt_bf16<<<4096, 256, 0, stream>>>(x, xb, 1048576);
        build_wcat<<<128, 256, 0, stream>>>(Wsq, Wsk, Wsv, Wf, wcat);
        gemm_bt<float><<<dim3(32, 1), 256, 0, stream>>>(xb, wcat, glog, 4096, 128, 2048);
        cumsum_logf<<<32, 256, 0, stream>>>(glog, bfv, cum);

        cvt_bf16<<<2048, 256, 0, stream>>>(Wq, Wb, 524288);
        gemm_bt<unsigned short><<<dim3(32, 16), 256, 0, stream>>>(xb, Wb, ybuf, 4096, 2048, 2048);
        shift_rope<true><<<2048, 256, 0, stream>>>(ybuf, 2048, 0, glog, 0, qbuf);

        cvt_bf16<<<2048, 256, 0, stream>>>(Wk, Wb, 524288);
        gemm_bt<unsigned short><<<dim3(32, 16), 256, 0, stream>>>(xb, Wb, ybuf, 4096, 2048, 2048);
        shift_rope<true><<<2048, 256, 0, stream>>>(ybuf, 2048, 0, glog, 16, kbuf);

        cvt_bf16<<<2048, 256, 0, stream>>>(Wv, Wb, 524288);
        gemm_bt<unsigned short><<<dim3(32, 16), 256, 0, stream>>>(xb, Wb, ybuf, 4096, 2048, 2048);
        shift_rope<false><<<2048, 256, 0, stream>>>(ybuf, 2048, 0, glog, 32, vbuf);
        transpose_v<<<dim3(64, 4, 32), dim3(32, 8), 0, stream>>>(vbuf, vt);

        flash_fwd<<<dim3(16, 32), 512, 0, stream>>>(qbuf, kbuf, vt, cum, ybuf);

        cvt_bf16<<<2048, 256, 0, stream>>>(Wo, Wb, 524288);
        gemm_bt<float><<<dim3(32, 16), 256, 0, stream>>>(ybuf, Wb, out, 4096, 2048, 2048);
    }
}